// Round 1
// baseline (326.648 us; speedup 1.0000x reference)
//
#include <hip/hip_runtime.h>

// Conv2d: x [3, 2048, 2048] f32, kernel [16, 3, 3, 3] f32, pad=1, stride=1
// out [16, 2048, 2048] f32.
// Memory-bound: ~268 MB write + ~50 MB read => ~50 us floor @ 6.3 TB/s.

#define CONV_H 2048
#define CONV_W 2048
#define CONV_IC 3
#define CONV_OC 16

// Transpose weights [oc][ic][kh][kw] -> [ic*9+kh*3+kw][oc] so the 16 OC
// weights of one tap are contiguous (wave-uniform s_load_dwordx16-friendly).
__global__ void conv_weight_transpose(const float* __restrict__ k,
                                      float* __restrict__ wt) {
    int t = threadIdx.x;
    if (t < CONV_OC * CONV_IC * 9) {
        int oc = t / 27;       // 27 = ic*kh*kw taps per oc
        int r  = t % 27;       // r = ic*9 + kh*3 + kw
        wt[r * CONV_OC + oc] = k[t];
    }
}

__global__ __launch_bounds__(256) void conv2d_main(const float* __restrict__ x,
                                                   const float* __restrict__ wt,
                                                   float* __restrict__ out) {
    const int tid = blockIdx.x * 256 + threadIdx.x;
    const int w4  = tid & (CONV_W / 4 - 1);   // 512 float4 positions per row
    const int h   = tid >> 9;
    const int w0  = w4 << 2;

    float acc[CONV_OC][4];
#pragma unroll
    for (int oc = 0; oc < CONV_OC; ++oc)
#pragma unroll
        for (int j = 0; j < 4; ++j) acc[oc][j] = 0.f;

#pragma unroll
    for (int ic = 0; ic < CONV_IC; ++ic) {
        const float* plane = x + (size_t)ic * CONV_H * CONV_W;
#pragma unroll
        for (int kh = 0; kh < 3; ++kh) {
            const int hy = h + kh - 1;
            if (hy >= 0 && hy < CONV_H) {
                const float* row = plane + (size_t)hy * CONV_W;
                float in[6];
                const float4 c = *reinterpret_cast<const float4*>(row + w0);
                in[0] = (w0 > 0) ? row[w0 - 1] : 0.f;
                in[1] = c.x; in[2] = c.y; in[3] = c.z; in[4] = c.w;
                in[5] = (w0 + 4 < CONV_W) ? row[w0 + 4] : 0.f;
#pragma unroll
                for (int kw = 0; kw < 3; ++kw) {
                    const float* wp = wt + ((ic * 3 + kh) * 3 + kw) * CONV_OC;
#pragma unroll
                    for (int oc = 0; oc < CONV_OC; ++oc) {
                        const float wv = wp[oc];
#pragma unroll
                        for (int j = 0; j < 4; ++j)
                            acc[oc][j] = fmaf(in[kw + j], wv, acc[oc][j]);
                    }
                }
            }
        }
    }

    float* obase = out + (size_t)h * CONV_W + w0;
#pragma unroll
    for (int oc = 0; oc < CONV_OC; ++oc) {
        float4 v = make_float4(acc[oc][0], acc[oc][1], acc[oc][2], acc[oc][3]);
        *reinterpret_cast<float4*>(obase + (size_t)oc * CONV_H * CONV_W) = v;
    }
}

extern "C" void kernel_launch(void* const* d_in, const int* in_sizes, int n_in,
                              void* d_out, int out_size, void* d_ws, size_t ws_size,
                              hipStream_t stream) {
    const float* x = (const float*)d_in[0];
    const float* k = (const float*)d_in[1];
    float* out = (float*)d_out;
    float* wt  = (float*)d_ws;   // 432 floats of transposed weights

    conv_weight_transpose<<<1, 512, 0, stream>>>(k, wt);

    const int total_threads = CONV_H * (CONV_W / 4);   // 1,048,576
    conv2d_main<<<total_threads / 256, 256, 0, stream>>>(x, wt, out);
}